// Round 1
// baseline (1057.883 us; speedup 1.0000x reference)
//
#include <hip/hip_runtime.h>
#include <math.h>

#define NROWS 4096
#define NCOLS 50257

struct Accum {
    double s_false;
    double s_correct;
    double s_mixed;
    double ce_sum;
    int    n_correct;
    int    pad[5];
};

// ---------------------------------------------------------------------------
// Kernel 1: one block per row. Online softmax (max, sum of exp(x-max)),
// argmax with first-index tie-break, logit at target. Writes probs/vf/vc,
// atomically accumulates ce_sum and n_correct.
// ---------------------------------------------------------------------------
__global__ __launch_bounds__(256) void mmce_rows(
    const float* __restrict__ in, const int* __restrict__ tgt,
    float* __restrict__ probs, float* __restrict__ vf, float* __restrict__ vc,
    Accum* __restrict__ acc)
{
    const int row = blockIdx.x;
    const int tid = threadIdx.x;
    const float* __restrict__ x = in + (size_t)row * NCOLS;

    float m = -INFINITY, s = 0.0f;
    float bv = -INFINITY;
    int   bi = 0x7fffffff;

    // peel to 16B alignment: base element index row*NCOLS, NCOLS%4==1
    const int e0mod = (int)(((size_t)row * NCOLS) & 3);
    const int head  = (4 - e0mod) & 3;

    if (tid < head) {
        float v = x[tid];
        float nm = fmaxf(m, v);
        s = s * __expf(m - nm) + __expf(v - nm);
        m = nm;
        if (v > bv) { bv = v; bi = tid; }
    }

    const float4* __restrict__ x4 = (const float4*)(x + head);
    const int nv = (NCOLS - head) >> 2;
    for (int vi = tid; vi < nv; vi += 256) {
        float4 v4 = x4[vi];
        int base = head + (vi << 2);
        float vmax = fmaxf(fmaxf(v4.x, v4.y), fmaxf(v4.z, v4.w));
        float nm = fmaxf(m, vmax);
        s = s * __expf(m - nm)
          + __expf(v4.x - nm) + __expf(v4.y - nm)
          + __expf(v4.z - nm) + __expf(v4.w - nm);
        m = nm;
        if (v4.x > bv) { bv = v4.x; bi = base; }
        if (v4.y > bv) { bv = v4.y; bi = base + 1; }
        if (v4.z > bv) { bv = v4.z; bi = base + 2; }
        if (v4.w > bv) { bv = v4.w; bi = base + 3; }
    }

    const int tstart = head + (nv << 2);
    const int tail = NCOLS - tstart;
    if (tid < tail) {
        float v = x[tstart + tid];
        float nm = fmaxf(m, v);
        s = s * __expf(m - nm) + __expf(v - nm);
        m = nm;
        if (v > bv) { bv = v; bi = tstart + tid; }
    }

    __shared__ float rm[256], rs[256], rv[256];
    __shared__ int   ri[256];
    rm[tid] = m; rs[tid] = s; rv[tid] = bv; ri[tid] = bi;
    __syncthreads();
    for (int off = 128; off > 0; off >>= 1) {
        if (tid < off) {
            float m1 = rm[tid],       s1 = rs[tid];
            float m2 = rm[tid + off], s2 = rs[tid + off];
            float nm = fmaxf(m1, m2);
            rs[tid] = s1 * __expf(m1 - nm) + s2 * __expf(m2 - nm);
            rm[tid] = nm;
            float v1 = rv[tid];       int i1 = ri[tid];
            float v2 = rv[tid + off]; int i2 = ri[tid + off];
            if (v2 > v1 || (v2 == v1 && i2 < i1)) { rv[tid] = v2; ri[tid] = i2; }
        }
        __syncthreads();
    }

    if (tid == 0) {
        float mfin = rm[0], sfin = rs[0];
        float lse = mfin + logf(sfin);
        int t = tgt[row];
        float xt = x[t];
        double ce = (double)lse - (double)xt;

        float p = 1.0f / sfin;                 // exp(max - lse) == 1/sum
        p = fminf(fmaxf(p, 1e-12f), 1.0f - 1e-12f);
        int matched = (ri[0] == t) ? 1 : 0;

        probs[row] = p;
        vf[row] = matched ? 0.0f : p;
        vc[row] = matched ? (1.0f - p) : 0.0f;

        atomicAdd(&acc->ce_sum, ce);
        if (matched) atomicAdd(&acc->n_correct, 1);
    }
}

// ---------------------------------------------------------------------------
// Kernel 2: pairwise Laplacian quadratic forms, all vectors staged in LDS.
// For each i: Af = sum_j K(i,j) vf_j ; Ac = sum_j K(i,j) vc_j ; then
// s_false += vf_i*Af, s_correct += vc_i*Ac, s_mixed += vc_i*Af.
// ---------------------------------------------------------------------------
__global__ __launch_bounds__(256) void mmce_pairs(
    const float* __restrict__ probs, const float* __restrict__ vfv,
    const float* __restrict__ vcv, Accum* __restrict__ acc)
{
    __shared__ float sp[NROWS];
    __shared__ float svf[NROWS];
    __shared__ float svc[NROWS];
    const int tid = threadIdx.x;
    for (int k = tid; k < NROWS; k += 256) {
        sp[k]  = probs[k];
        svf[k] = vfv[k];
        svc[k] = vcv[k];
    }
    __syncthreads();

    double tf = 0.0, tc = 0.0, tm = 0.0;
    for (int i = blockIdx.x; i < NROWS; i += gridDim.x) {
        float pi  = sp[i];
        float vfi = svf[i];
        float vci = svc[i];
        float af = 0.0f, ac = 0.0f;
        for (int j = tid; j < NROWS; j += 256) {
            float kv = __expf(-2.5f * fabsf(pi - sp[j]));
            af += kv * svf[j];
            ac += kv * svc[j];
        }
        tf += (double)vfi * (double)af;
        tc += (double)vci * (double)ac;
        tm += (double)vci * (double)af;
    }

    __shared__ double r[256];
    r[tid] = tf; __syncthreads();
    for (int off = 128; off > 0; off >>= 1) {
        if (tid < off) r[tid] += r[tid + off];
        __syncthreads();
    }
    if (tid == 0) atomicAdd(&acc->s_false, r[0]);
    __syncthreads();

    r[tid] = tc; __syncthreads();
    for (int off = 128; off > 0; off >>= 1) {
        if (tid < off) r[tid] += r[tid + off];
        __syncthreads();
    }
    if (tid == 0) atomicAdd(&acc->s_correct, r[0]);
    __syncthreads();

    r[tid] = tm; __syncthreads();
    for (int off = 128; off > 0; off >>= 1) {
        if (tid < off) r[tid] += r[tid + off];
        __syncthreads();
    }
    if (tid == 0) atomicAdd(&acc->s_mixed, r[0]);
}

// ---------------------------------------------------------------------------
// Kernel 3: scalar epilogue (safe_div + sqrt + ce mean)
// ---------------------------------------------------------------------------
__global__ void mmce_final(const Accum* __restrict__ acc, float* __restrict__ out)
{
    double nc = (double)acc->n_correct;
    double nf = (double)NROWS - nc;
    double denf = nf * nf;
    double denc = nc * nc;
    double denm = nf * nc;
    double pf = (denf > 0.0) ? acc->s_false   / fmax(denf, 1.0) : 0.0;
    double pc = (denc > 0.0) ? acc->s_correct / fmax(denc, 1.0) : 0.0;
    double pm = (denm > 0.0) ? 2.0 * acc->s_mixed / fmax(denm, 1.0) : 0.0;
    double mmce = sqrt(fmax(pf + pc - pm, 0.0));
    double ce = acc->ce_sum / (double)NROWS;
    out[0] = (float)(mmce + ce);
}

extern "C" void kernel_launch(void* const* d_in, const int* in_sizes, int n_in,
                              void* d_out, int out_size, void* d_ws, size_t ws_size,
                              hipStream_t stream)
{
    const float* in  = (const float*)d_in[0];
    const int*   tgt = (const int*)d_in[1];
    float* out = (float*)d_out;

    char* ws = (char*)d_ws;
    Accum* acc   = (Accum*)ws;
    float* probs = (float*)(ws + 64);
    float* vfv   = probs + NROWS;
    float* vcv   = vfv + NROWS;

    hipMemsetAsync(acc, 0, sizeof(Accum), stream);
    hipLaunchKernelGGL(mmce_rows, dim3(NROWS), dim3(256), 0, stream,
                       in, tgt, probs, vfv, vcv, acc);
    hipLaunchKernelGGL(mmce_pairs, dim3(256), dim3(256), 0, stream,
                       probs, vfv, vcv, acc);
    hipLaunchKernelGGL(mmce_final, dim3(1), dim3(1), 0, stream, acc, out);
}

// Round 2
// 1047.064 us; speedup vs baseline: 1.0103x; 1.0103x over previous
//
#include <hip/hip_runtime.h>
#include <math.h>

#define NROWS 4096
#define NCOLS 50257

// ---------------------------------------------------------------------------
// Kernel 1: one block per row. Online softmax (max, sum of exp(x-max)),
// argmax with first-index tie-break, logit at target. Writes probs/vf/vc,
// per-row ce and match flags. NO atomics.
// ---------------------------------------------------------------------------
__global__ __launch_bounds__(256) void mmce_rows(
    const float* __restrict__ in, const int* __restrict__ tgt,
    float* __restrict__ probs, float* __restrict__ vf, float* __restrict__ vc,
    float* __restrict__ ce, int* __restrict__ match)
{
    const int row = blockIdx.x;
    const int tid = threadIdx.x;
    const float* __restrict__ x = in + (size_t)row * NCOLS;

    float m = -INFINITY, s = 0.0f;
    float bv = -INFINITY;
    int   bi = 0x7fffffff;

    // peel to 16B alignment: base element index row*NCOLS, NCOLS%4==1
    const int e0mod = (int)(((size_t)row * NCOLS) & 3);
    const int head  = (4 - e0mod) & 3;

    if (tid < head) {
        float v = x[tid];
        float nm = fmaxf(m, v);
        s = s * __expf(m - nm) + __expf(v - nm);
        m = nm;
        if (v > bv) { bv = v; bi = tid; }
    }

    const float4* __restrict__ x4 = (const float4*)(x + head);
    const int nv = (NCOLS - head) >> 2;
    for (int vi = tid; vi < nv; vi += 256) {
        float4 v4 = x4[vi];
        int base = head + (vi << 2);
        float vmax = fmaxf(fmaxf(v4.x, v4.y), fmaxf(v4.z, v4.w));
        float nm = fmaxf(m, vmax);
        s = s * __expf(m - nm)
          + __expf(v4.x - nm) + __expf(v4.y - nm)
          + __expf(v4.z - nm) + __expf(v4.w - nm);
        m = nm;
        if (v4.x > bv) { bv = v4.x; bi = base; }
        if (v4.y > bv) { bv = v4.y; bi = base + 1; }
        if (v4.z > bv) { bv = v4.z; bi = base + 2; }
        if (v4.w > bv) { bv = v4.w; bi = base + 3; }
    }

    const int tstart = head + (nv << 2);
    const int tail = NCOLS - tstart;
    if (tid < tail) {
        float v = x[tstart + tid];
        float nm = fmaxf(m, v);
        s = s * __expf(m - nm) + __expf(v - nm);
        m = nm;
        if (v > bv) { bv = v; bi = tstart + tid; }
    }

    __shared__ float rm[256], rs[256], rv[256];
    __shared__ int   ri[256];
    rm[tid] = m; rs[tid] = s; rv[tid] = bv; ri[tid] = bi;
    __syncthreads();
    for (int off = 128; off > 0; off >>= 1) {
        if (tid < off) {
            float m1 = rm[tid],       s1 = rs[tid];
            float m2 = rm[tid + off], s2 = rs[tid + off];
            float nm = fmaxf(m1, m2);
            rs[tid] = s1 * __expf(m1 - nm) + s2 * __expf(m2 - nm);
            rm[tid] = nm;
            float v1 = rv[tid];       int i1 = ri[tid];
            float v2 = rv[tid + off]; int i2 = ri[tid + off];
            if (v2 > v1 || (v2 == v1 && i2 < i1)) { rv[tid] = v2; ri[tid] = i2; }
        }
        __syncthreads();
    }

    if (tid == 0) {
        float mfin = rm[0], sfin = rs[0];
        float lse = mfin + logf(sfin);
        int t = tgt[row];
        float xt = x[t];

        float p = 1.0f / sfin;                 // exp(max - lse) == 1/sum
        p = fminf(fmaxf(p, 1e-12f), 1.0f - 1e-12f);
        int matched = (ri[0] == t) ? 1 : 0;

        probs[row] = p;
        vf[row] = matched ? 0.0f : p;
        vc[row] = matched ? (1.0f - p) : 0.0f;
        ce[row] = lse - xt;
        match[row] = matched;
    }
}

// ---------------------------------------------------------------------------
// Kernel 2: pairwise Laplacian quadratic forms, all vectors staged in LDS.
// Per-block partial sums written to global (no atomics).
// ---------------------------------------------------------------------------
__global__ __launch_bounds__(256) void mmce_pairs(
    const float* __restrict__ probs, const float* __restrict__ vfv,
    const float* __restrict__ vcv,
    double* __restrict__ pf, double* __restrict__ pc, double* __restrict__ pm)
{
    __shared__ float sp[NROWS];
    __shared__ float svf[NROWS];
    __shared__ float svc[NROWS];
    const int tid = threadIdx.x;
    for (int k = tid; k < NROWS; k += 256) {
        sp[k]  = probs[k];
        svf[k] = vfv[k];
        svc[k] = vcv[k];
    }
    __syncthreads();

    double tf = 0.0, tc = 0.0, tm = 0.0;
    for (int i = blockIdx.x; i < NROWS; i += gridDim.x) {
        float pi  = sp[i];
        float vfi = svf[i];
        float vci = svc[i];
        float af = 0.0f, ac = 0.0f;
        for (int j = tid; j < NROWS; j += 256) {
            float kv = __expf(-2.5f * fabsf(pi - sp[j]));
            af += kv * svf[j];
            ac += kv * svc[j];
        }
        tf += (double)vfi * (double)af;
        tc += (double)vci * (double)ac;
        tm += (double)vci * (double)af;
    }

    __shared__ double rf[256], rc[256], rm2[256];
    rf[tid] = tf; rc[tid] = tc; rm2[tid] = tm;
    __syncthreads();
    for (int off = 128; off > 0; off >>= 1) {
        if (tid < off) {
            rf[tid]  += rf[tid + off];
            rc[tid]  += rc[tid + off];
            rm2[tid] += rm2[tid + off];
        }
        __syncthreads();
    }
    if (tid == 0) {
        pf[blockIdx.x] = rf[0];
        pc[blockIdx.x] = rc[0];
        pm[blockIdx.x] = rm2[0];
    }
}

// ---------------------------------------------------------------------------
// Kernel 3: final reduction (ce mean, match count, partials) + epilogue
// ---------------------------------------------------------------------------
__global__ __launch_bounds__(256) void mmce_final(
    const float* __restrict__ ce, const int* __restrict__ match,
    const double* __restrict__ pf, const double* __restrict__ pc,
    const double* __restrict__ pm, float* __restrict__ out)
{
    const int tid = threadIdx.x;

    double ces = 0.0;
    int    cnt = 0;
    for (int k = tid; k < NROWS; k += 256) {
        ces += (double)ce[k];
        cnt += match[k];
    }

    __shared__ double rce[256], rf[256], rc[256], rm[256];
    __shared__ int    rcnt[256];
    rce[tid] = ces; rcnt[tid] = cnt;
    rf[tid] = pf[tid]; rc[tid] = pc[tid]; rm[tid] = pm[tid];
    __syncthreads();
    for (int off = 128; off > 0; off >>= 1) {
        if (tid < off) {
            rce[tid]  += rce[tid + off];
            rcnt[tid] += rcnt[tid + off];
            rf[tid]   += rf[tid + off];
            rc[tid]   += rc[tid + off];
            rm[tid]   += rm[tid + off];
        }
        __syncthreads();
    }

    if (tid == 0) {
        double nc = (double)rcnt[0];
        double nf = (double)NROWS - nc;
        double denf = nf * nf;
        double denc = nc * nc;
        double denm = nf * nc;
        double vpf = (denf > 0.0) ? rf[0] / fmax(denf, 1.0) : 0.0;
        double vpc = (denc > 0.0) ? rc[0] / fmax(denc, 1.0) : 0.0;
        double vpm = (denm > 0.0) ? 2.0 * rm[0] / fmax(denm, 1.0) : 0.0;
        double mmce = sqrt(fmax(vpf + vpc - vpm, 0.0));
        double cem = rce[0] / (double)NROWS;
        out[0] = (float)(mmce + cem);
    }
}

extern "C" void kernel_launch(void* const* d_in, const int* in_sizes, int n_in,
                              void* d_out, int out_size, void* d_ws, size_t ws_size,
                              hipStream_t stream)
{
    const float* in  = (const float*)d_in[0];
    const int*   tgt = (const int*)d_in[1];
    float* out = (float*)d_out;

    char* ws = (char*)d_ws;
    float*  probs = (float*)ws;                 // 4096 f32
    float*  vfv   = probs + NROWS;              // 4096 f32
    float*  vcv   = vfv + NROWS;                // 4096 f32
    float*  cev   = vcv + NROWS;                // 4096 f32
    int*    match = (int*)(cev + NROWS);        // 4096 i32
    double* pf    = (double*)(match + NROWS);   // 256 f64 (8B aligned)
    double* pc    = pf + 256;
    double* pm    = pc + 256;

    hipLaunchKernelGGL(mmce_rows, dim3(NROWS), dim3(256), 0, stream,
                       in, tgt, probs, vfv, vcv, cev, match);
    hipLaunchKernelGGL(mmce_pairs, dim3(256), dim3(256), 0, stream,
                       probs, vfv, vcv, pf, pc, pm);
    hipLaunchKernelGGL(mmce_final, dim3(1), dim3(256), 0, stream,
                       cev, match, pf, pc, pm, out);
}